// Round 2
// baseline (3629.612 us; speedup 1.0000x reference)
//
#include <hip/hip_runtime.h>

// GumbelDecoderEncoder: B=16384, E=256, V=128, T=16, TAU=1.
// Key facts exploited (carried over from the fp32 kernel):
//  * y is numerically EXACTLY one-hot or zero, so input-side matmuls are
//    table lookups (DecTab/EncTab row 128 = zero-token case).
//  * argmax(softmax((l+g)/tau)) == argmax(l+g).
//  * Encoder sieve can never fire: reconst = final encoder state.
//  * Row-independent; decoder hidden state is wave-private LDS.
// R2: encoder GRU matmul on MFMA (matrix pipe was 0% utilized). Encoder-only
// is precision-safe: it feeds ONLY reconst (abs-tol output); decoder/logits/
// argmax path kept BIT-EXACT fp32 -> utterance and N identical to the passing
// kernel regardless of encoder changes.
// R2b: MFMA fragment type = ext_vector_type(8) short (the env-verified
// signature for __builtin_amdgcn_mfma_f32_16x16x32_bf16 on gfx950), replacing
// R1's __bf16 vectors -- only compile-risk candidate for the container failure.
// Precision: 3-way bf16 split (h=hi+mid+lo, w likewise), 6 MFMA products keep
// all terms >= 2^-24 rel -> reconst error ~1e-7 (fp32-class). A and B use the
// same k-slot mapping, so any k-permutation in the HW sub-layout cancels.
// LDS 64KB exactly: hdec 32KB (wave-private, untouched) + henc 32KB
// (block-shared fp32, XOR-swizzled). Cross-wave token exchange reuses the
// N output region as scratch (overwritten by float N at the end).

namespace {
constexpr int kB  = 16384;
constexpr int kE  = 256;
constexpr int kV  = 128;
constexpr int kT  = 16;
constexpr int kG3 = 768;

constexpr int kOffWdhhT  = 0;                       // [256][768] f32 dec Whh^T (k-major)
constexpr int kOffWe2dT  = kG3 * kE;                // [256][128] f32
constexpr int kOffDecTab = kOffWe2dT + kV * kE;     // [129][768] f32
constexpr int kOffEncTab = kOffDecTab + 129 * kG3;  // [129][768] f32
constexpr int kOffBTab   = kOffEncTab + 129 * kG3;  // enc Whh bf16 3-split (u16)
constexpr int kBCount    = 32 * kG3 * 8;            // 196608 u16 per split level
// ws bytes: 427520*4 + 3*196608*2 = 2,889,728 (~2.76 MB)
}

typedef short bf16x8 __attribute__((ext_vector_type(8)));  // 8 bf16 as i16 (4 VGPRs)
typedef float f32x4  __attribute__((ext_vector_type(4)));
typedef unsigned short u16;

__device__ __forceinline__ float sigmf(float v) { return 1.0f / (1.0f + expf(-v)); }
__device__ __forceinline__ float gumbelf(float u) {
  return -logf(-logf(u + 1e-10f) + 1e-10f);
}

__device__ __forceinline__ f32x4 mfma16(bf16x8 a, bf16x8 b, f32x4 c) {
  return __builtin_amdgcn_mfma_f32_16x16x32_bf16(a, b, c, 0, 0, 0);
}

struct Bf3 { bf16x8 h, m, l; };

// exact 3-way bf16 split: f = hi + mid + f2 exactly (truncating Dekker split),
// lo = trunc-to-bf16(f2); dropped bits are < 2^-24 relative.
__device__ __forceinline__ Bf3 split3(float4 a, float4 b) {
  const float v[8] = {a.x, a.y, a.z, a.w, b.x, b.y, b.z, b.w};
  union { bf16x8 b8; u16 u[8]; } H, M, L;
#pragma unroll
  for (int e = 0; e < 8; ++e) {
    const float f = v[e];
    const unsigned hb = __float_as_uint(f) & 0xffff0000u;
    const float f1 = f - __uint_as_float(hb);
    const unsigned mb = __float_as_uint(f1) & 0xffff0000u;
    const float f2 = f1 - __uint_as_float(mb);
    H.u[e] = (u16)(hb >> 16);
    M.u[e] = (u16)(mb >> 16);
    L.u[e] = (u16)(__float_as_uint(f2) >> 16);
  }
  Bf3 r; r.h = H.b8; r.m = M.b8; r.l = L.b8;
  return r;
}

// swizzled henc index: 8-float chunks XORed by row&7 -> spread A-read banks
__device__ __forceinline__ int hidx(int row, int col) {
  return row * kE + ((((col >> 3) ^ (row & 7)) << 3) | (col & 7));
}

// ---- prepass 1: k-major transposes of dec Whh and We2d ----
__global__ void prep_transpose(const float* __restrict__ dWhh,
                               const float* __restrict__ We2d,
                               float* __restrict__ ws) {
  const int n1 = kG3 * kE;
  const int n2 = n1 + kV * kE;
  for (int i = blockIdx.x * blockDim.x + threadIdx.x; i < n2;
       i += gridDim.x * blockDim.x) {
    if (i < n1) {
      const int k = i / kG3, j = i - k * kG3;
      ws[i] = dWhh[j * kE + k];
    } else {
      const int t = i - n1;
      const int k = t / kV, v = t - k * kV;
      ws[i] = We2d[v * kE + k];
    }
  }
}

// ---- prepass 2: token->gi tables (v==128 is the zero-token row) ----
__global__ void prep_tables(const float* __restrict__ Wih,
                            const float* __restrict__ Wd2e,
                            const float* __restrict__ bd2e,
                            const float* __restrict__ bih,
                            float* __restrict__ tab) {
  const int i = blockIdx.x * blockDim.x + threadIdx.x;
  if (i >= 129 * kG3) return;
  const int v = i / kG3, j = i - v * kG3;
  const float* wr = Wih + j * kE;
  float acc = 0.0f;
  if (v < kV) {
    for (int k = 0; k < kE; ++k) acc = fmaf(wr[k], Wd2e[k * kV + v] + bd2e[k], acc);
  } else {
    for (int k = 0; k < kE; ++k) acc = fmaf(wr[k], bd2e[k], acc);
  }
  tab[i] = acc + bih[j];
}

// ---- prepass 3: enc Whh^T -> bf16 3-way split MFMA B-fragment table ----
// record idx = kg*768 + j (kg = k/8), holds e=0..7 with k = kg*8+e.
__global__ void prep_bsplit(const float* __restrict__ eWhh,
                            u16* __restrict__ bt) {
  const int idx = blockIdx.x * blockDim.x + threadIdx.x;
  if (idx >= 32 * kG3) return;
  const int j = idx % kG3;
  const int kg = idx / kG3;
  u16* ph = bt + (size_t)idx * 8;
  u16* pm = ph + kBCount;
  u16* pl = pm + kBCount;
  const float* src = eWhh + j * kE + kg * 8;
#pragma unroll
  for (int e = 0; e < 8; ++e) {
    const float f = src[e];
    const unsigned hb = __float_as_uint(f) & 0xffff0000u;
    const float f1 = f - __uint_as_float(hb);
    const unsigned mb = __float_as_uint(f1) & 0xffff0000u;
    const float f2 = f1 - __uint_as_float(mb);
    ph[e] = (u16)(hb >> 16);
    pm[e] = (u16)(mb >> 16);
    pl[e] = (u16)(__float_as_uint(f2) >> 16);
  }
}

// ---- decoder fp32 path (UNCHANGED: bit-exact vs passing kernel) ----
__device__ __forceinline__ void gru_half(float acc[8][3][4],
                                         const float (*__restrict__ h)[8],
                                         const float* __restrict__ WT,
                                         const int e0) {
#pragma unroll
  for (int r = 0; r < 8; ++r)
#pragma unroll
    for (int g = 0; g < 3; ++g)
#pragma unroll
      for (int c = 0; c < 4; ++c) acc[r][g][c] = 0.0f;
#pragma unroll 2
  for (int k = 0; k < kE; ++k) {
    const float4 hA = *(const float4*)(&h[k][0]);
    const float4 hB = *(const float4*)(&h[k][4]);
    const float* wp = WT + k * kG3 + e0;
    const float4 w0 = *(const float4*)(wp);
    const float4 w1 = *(const float4*)(wp + 256);
    const float4 w2 = *(const float4*)(wp + 512);
    const float hv[8] = {hA.x, hA.y, hA.z, hA.w, hB.x, hB.y, hB.z, hB.w};
    const float wv[3][4] = {{w0.x, w0.y, w0.z, w0.w},
                            {w1.x, w1.y, w1.z, w1.w},
                            {w2.x, w2.y, w2.z, w2.w}};
#pragma unroll
    for (int r = 0; r < 8; ++r)
#pragma unroll
      for (int g = 0; g < 3; ++g)
#pragma unroll
        for (int c = 0; c < 4; ++c)
          acc[r][g][c] = fmaf(hv[r], wv[g][c], acc[r][g][c]);
  }
}

__device__ __forceinline__ void gru_pointwise(float acc[8][3][4],
                                              float (*__restrict__ h)[8],
                                              const float* __restrict__ Tab,
                                              const int tok[8],
                                              const float4& br4, const float4& bz4,
                                              const float4& bn4, const int e0) {
  const float br[4] = {br4.x, br4.y, br4.z, br4.w};
  const float bz[4] = {bz4.x, bz4.y, bz4.z, bz4.w};
  const float bn[4] = {bn4.x, bn4.y, bn4.z, bn4.w};
#pragma unroll
  for (int r = 0; r < 8; ++r) {
    const float* gp = Tab + tok[r] * kG3 + e0;
    const float4 g0 = *(const float4*)(gp);
    const float4 g1 = *(const float4*)(gp + 256);
    const float4 g2 = *(const float4*)(gp + 512);
    const float gi[3][4] = {{g0.x, g0.y, g0.z, g0.w},
                            {g1.x, g1.y, g1.z, g1.w},
                            {g2.x, g2.y, g2.z, g2.w}};
#pragma unroll
    for (int c = 0; c < 4; ++c) {
      const float rg = sigmf(gi[0][c] + acc[r][0][c] + br[c]);
      const float zg = sigmf(gi[1][c] + acc[r][1][c] + bz[c]);
      const float ng = tanhf(gi[2][c] + rg * (acc[r][2][c] + bn[c]));
      acc[r][0][c] = ng;
      acc[r][1][c] = zg;
    }
  }
#pragma unroll
  for (int c = 0; c < 4; ++c) {
    const int e = e0 + c;
    const float4 hA = *(const float4*)(&h[e][0]);
    const float4 hB = *(const float4*)(&h[e][4]);
    const float ho[8] = {hA.x, hA.y, hA.z, hA.w, hB.x, hB.y, hB.z, hB.w};
    float hn[8];
#pragma unroll
    for (int r = 0; r < 8; ++r)
      hn[r] = (1.0f - acc[r][1][c]) * acc[r][0][c] + acc[r][1][c] * ho[r];
    *(float4*)(&h[e][0]) = make_float4(hn[0], hn[1], hn[2], hn[3]);
    *(float4*)(&h[e][4]) = make_float4(hn[4], hn[5], hn[6], hn[7]);
  }
}

__launch_bounds__(256, 2)
__global__ void gumbel_fused(const float* __restrict__ x,
                             const float* __restrict__ unoise,
                             const float* __restrict__ dbhh,
                             const float* __restrict__ dbe2d,
                             const float* __restrict__ ebhh,
                             const float* __restrict__ ws,
                             float* __restrict__ out) {
  const float* WdhhT  = ws + kOffWdhhT;
  const float* We2dT  = ws + kOffWe2dT;
  const float* DecTab = ws + kOffDecTab;
  const float* EncTab = ws + kOffEncTab;
  const u16* Bh_t = (const u16*)(ws + kOffBTab);
  const u16* Bm_t = Bh_t + kBCount;
  const u16* Bl_t = Bh_t + 2 * kBCount;

  __shared__ __align__(16) float hd_s[4][kE][8];  // decoder state, wave-private 32KB
  __shared__ __align__(16) float henc[32 * kE];   // encoder state, block-shared 32KB

  const int tid  = (int)threadIdx.x;
  const int w    = tid >> 6;
  const int jx   = tid & 63;
  const int brow0 = (int)blockIdx.x * 32;
  const int row0  = brow0 + w * 8;   // this wave's 8 decoder rows
  const int e0   = jx * 4;

  float (*hd)[8] = hd_s[w];

  // init: hdec = x (coalesced), henc = 0
  for (int i = jx; i < kE * 8; i += 64) {
    const int r = i >> 8, k = i & (kE - 1);
    hd[k][r] = x[(size_t)(row0 + r) * kE + k];
  }
  for (int i = tid; i < 32 * kE; i += 256) henc[i] = 0.0f;
  __syncthreads();

  int tok[8], Nn[8];
  bool alive[8];
#pragma unroll
  for (int r = 0; r < 8; ++r) { tok[r] = kV; Nn[r] = kT; alive[r] = true; }

  const float4 dbr = *(const float4*)(dbhh + e0);
  const float4 dbz = *(const float4*)(dbhh + 256 + e0);
  const float4 dbn = *(const float4*)(dbhh + 512 + e0);
  const float2 be2 = *(const float2*)(dbe2d + 2 * jx);

  // encoder per-lane constants (MFMA D layout: col=lane&15, row=(lane>>4)*4+reg)
  const int l15  = jx & 15;
  const int ksub = jx >> 4;
  const int arow0 = l15, arow1 = l15 + 16;
  const int a0base = arow0 * kE, a1base = arow1 * kE;
  const int a0m7 = arow0 & 7, a1m7 = arow1 & 7;
  float ebr[4], ebz[4], ebn[4];
#pragma unroll
  for (int nn = 0; nn < 4; ++nn) {
    const int ec = (w << 6) + (nn << 4) + l15;
    ebr[nn] = ebhh[ec];
    ebz[nn] = ebhh[kE + ec];
    ebn[nn] = ebhh[2 * kE + ec];
  }

  const size_t uttN = (size_t)kB * kT * kV;
  int* tokg = (int*)(out + uttN);  // reuse N region as cross-wave tok scratch

  float acc[8][3][4];
  const f32x4 zero4 = {0.0f, 0.0f, 0.0f, 0.0f};

  for (int t = 0; t < kT; ++t) {
    // ---- decoder GRU (fp32, bit-exact; uses tok from previous step) ----
    gru_half(acc, hd, WdhhT, e0);
    gru_pointwise(acc, hd, DecTab, tok, dbr, dbz, dbn, e0);
    __syncthreads();

    // ---- logits + gumbel + argmax; lane covers cols 2jx, 2jx+1 ----
    float l0[8], l1[8];
#pragma unroll
    for (int r = 0; r < 8; ++r) { l0[r] = 0.0f; l1[r] = 0.0f; }
#pragma unroll 2
    for (int k = 0; k < kE; ++k) {
      const float4 hA = *(const float4*)(&hd[k][0]);
      const float4 hB = *(const float4*)(&hd[k][4]);
      const float2 wv = *(const float2*)(We2dT + k * kV + 2 * jx);
      const float hv[8] = {hA.x, hA.y, hA.z, hA.w, hB.x, hB.y, hB.z, hB.w};
#pragma unroll
      for (int r = 0; r < 8; ++r) {
        l0[r] = fmaf(hv[r], wv.x, l0[r]);
        l1[r] = fmaf(hv[r], wv.y, l1[r]);
      }
    }
    const float* up = unoise + ((size_t)t * kB + row0) * kV + 2 * jx;
#pragma unroll
    for (int r = 0; r < 8; ++r) {
      const float2 u = *(const float2*)(up + (size_t)r * kV);
      const float a0 = l0[r] + be2.x + gumbelf(u.x);
      const float a1 = l1[r] + be2.y + gumbelf(u.y);
      float mv; int mi;
      if (a1 > a0) { mv = a1; mi = 2 * jx + 1; } else { mv = a0; mi = 2 * jx; }
#pragma unroll
      for (int off = 32; off >= 1; off >>= 1) {
        const float ov = __shfl_xor(mv, off, 64);
        const int   oi = __shfl_xor(mi, off, 64);
        if (ov > mv || (ov == mv && oi < mi)) { mv = ov; mi = oi; }
      }
      const bool ended = (mi == 0);
      if (ended) Nn[r] = (Nn[r] < t) ? Nn[r] : t;
      const bool anew = alive[r] && !ended;
      alive[r] = anew;
      tok[r] = anew ? mi : kV;  // kV == zero-token marker
      if (jx == r) tokg[row0 + r] = tok[r];
      float2 pr;
      pr.x = (anew && mi == 2 * jx) ? 1.0f : 0.0f;
      pr.y = (anew && mi == 2 * jx + 1) ? 1.0f : 0.0f;
      *reinterpret_cast<float2*>(
          out + ((size_t)(row0 + r) * kT + t) * kV + 2 * jx) = pr;
    }

    // ---- encoder gh = henc @ eWhh^T via MFMA (3-way bf16 split, 6 products) ----
    // wave w owns e-cols [64w,64w+64) of all 3 gates; block shares 32 rows.
    f32x4 eacc[2][12];
#pragma unroll
    for (int m = 0; m < 2; ++m)
#pragma unroll
      for (int nt = 0; nt < 12; ++nt) eacc[m][nt] = zero4;

#pragma unroll 2
    for (int kt = 0; kt < 8; ++kt) {
      const int c0 = ((kt << 2) + ksub) ^ a0m7;
      const int c1 = ((kt << 2) + ksub) ^ a1m7;
      const float4 f00 = *(const float4*)&henc[a0base + (c0 << 3)];
      const float4 f01 = *(const float4*)&henc[a0base + (c0 << 3) + 4];
      const float4 f10 = *(const float4*)&henc[a1base + (c1 << 3)];
      const float4 f11 = *(const float4*)&henc[a1base + (c1 << 3) + 4];
      const Bf3 A0 = split3(f00, f01);
      const Bf3 A1 = split3(f10, f11);
      const int recb = (((kt << 2) + ksub) * kG3 + (w << 6) + l15) * 8;
#pragma unroll
      for (int nt = 0; nt < 12; ++nt) {
        const int off = recb + ((nt >> 2) * 256 + (nt & 3) * 16) * 8;
        const bf16x8 Bh = *reinterpret_cast<const bf16x8*>(Bh_t + off);
        const bf16x8 Bm = *reinterpret_cast<const bf16x8*>(Bm_t + off);
        const bf16x8 Bl = *reinterpret_cast<const bf16x8*>(Bl_t + off);
        eacc[0][nt] = mfma16(A0.h, Bh, eacc[0][nt]);
        eacc[1][nt] = mfma16(A1.h, Bh, eacc[1][nt]);
        eacc[0][nt] = mfma16(A0.h, Bm, eacc[0][nt]);
        eacc[1][nt] = mfma16(A1.h, Bm, eacc[1][nt]);
        eacc[0][nt] = mfma16(A0.m, Bh, eacc[0][nt]);
        eacc[1][nt] = mfma16(A1.m, Bh, eacc[1][nt]);
        eacc[0][nt] = mfma16(A0.h, Bl, eacc[0][nt]);
        eacc[1][nt] = mfma16(A1.h, Bl, eacc[1][nt]);
        eacc[0][nt] = mfma16(A0.l, Bh, eacc[0][nt]);
        eacc[1][nt] = mfma16(A1.l, Bh, eacc[1][nt]);
        eacc[0][nt] = mfma16(A0.m, Bm, eacc[0][nt]);
        eacc[1][nt] = mfma16(A1.m, Bm, eacc[1][nt]);
      }
    }
    __syncthreads();  // all waves done READING henc (+ tokg visible)

    // ---- encoder pointwise: gates + state update (writes henc) ----
#pragma unroll
    for (int m = 0; m < 2; ++m) {
#pragma unroll
      for (int j2 = 0; j2 < 4; ++j2) {
        const int row = (m << 4) + (ksub << 2) + j2;
        const int tk = tokg[brow0 + row];
        const float* gp = EncTab + tk * kG3;
#pragma unroll
        for (int nn = 0; nn < 4; ++nn) {
          const int ec = (w << 6) + (nn << 4) + l15;
          const float rg = sigmf(gp[ec] + eacc[m][nn][j2] + ebr[nn]);
          const float zg = sigmf(gp[kE + ec] + eacc[m][4 + nn][j2] + ebz[nn]);
          const float ng = tanhf(gp[2 * kE + ec] + rg * (eacc[m][8 + nn][j2] + ebn[nn]));
          const int hx = hidx(row, ec);
          const float ho = henc[hx];
          henc[hx] = (1.0f - zg) * ng + zg * ho;
        }
      }
    }
    __syncthreads();  // henc writes done before next step's MFMA reads
  }

  // ---- outputs: N (overwrites tok scratch) then reconst = final henc ----
#pragma unroll
  for (int r = 0; r < 8; ++r)
    if (jx == r) out[uttN + row0 + r] = (float)Nn[r];
  for (int i = tid; i < 32 * kE; i += 256) {
    const int row = i >> 8, col = i & (kE - 1);
    out[uttN + kB + (size_t)(brow0 + row) * kE + col] = henc[hidx(row, col)];
  }
}

extern "C" void kernel_launch(void* const* d_in, const int* in_sizes, int n_in,
                              void* d_out, int out_size, void* d_ws, size_t ws_size,
                              hipStream_t stream) {
  (void)in_sizes; (void)n_in; (void)out_size; (void)ws_size;
  const float* x      = (const float*)d_in[0];
  // d_in[1] = global_idxes (unused by reference)
  const float* unoise = (const float*)d_in[2];
  const float* dWd2e  = (const float*)d_in[3];
  const float* dbd2e  = (const float*)d_in[4];
  const float* dWih   = (const float*)d_in[5];
  const float* dWhh   = (const float*)d_in[6];
  const float* dbih   = (const float*)d_in[7];
  const float* dbhh   = (const float*)d_in[8];
  const float* dWe2d  = (const float*)d_in[9];
  const float* dbe2d  = (const float*)d_in[10];
  const float* eWd2e  = (const float*)d_in[11];
  const float* ebd2e  = (const float*)d_in[12];
  const float* eWih   = (const float*)d_in[13];
  const float* eWhh   = (const float*)d_in[14];
  const float* ebih   = (const float*)d_in[15];
  const float* ebhh   = (const float*)d_in[16];
  float* ws = (float*)d_ws;  // needs 2,889,728 bytes (~2.76 MB)

  prep_transpose<<<896, 256, 0, stream>>>(dWhh, dWe2d, ws);
  prep_tables<<<(129 * kG3 + 255) / 256, 256, 0, stream>>>(
      dWih, dWd2e, dbd2e, dbih, ws + kOffDecTab);
  prep_tables<<<(129 * kG3 + 255) / 256, 256, 0, stream>>>(
      eWih, eWd2e, ebd2e, ebih, ws + kOffEncTab);
  prep_bsplit<<<(32 * kG3 + 255) / 256, 256, 0, stream>>>(
      eWhh, (u16*)(ws + kOffBTab));
  gumbel_fused<<<kB / 32, 256, 0, stream>>>(
      x, unoise, dbhh, dbe2d, ebhh, ws, (float*)d_out);
}